// Round 4
// baseline (699.755 us; speedup 1.0000x reference)
//
#include <hip/hip_runtime.h>
#include <stdint.h>

typedef unsigned short u16;
typedef unsigned int   u32;
typedef short bf16x8 __attribute__((ext_vector_type(8)));
typedef short bf16x4 __attribute__((ext_vector_type(4)));
typedef float floatx4 __attribute__((ext_vector_type(4)));

// ---- ws layout (u16 element offsets), total 64 MB ----
#define OFF_XQ   0u
#define OFF_XK   4194304u
#define OFF_XV   8388608u
#define OFF_WQ   12582912u
#define OFF_WK   13631488u
#define OFF_WV   14680064u
#define OFF_WO   15728640u
#define OFF_QH   16777216u
#define OFF_KH   20971520u
#define OFF_VT   25165824u
#define OFF_CTX  29360128u

__device__ __forceinline__ u16 f2b(float f){
  u32 u = __float_as_uint(f);
  u = (u + 0x7fffu + ((u >> 16) & 1u)) >> 16;
  return (u16)u;
}
__device__ __forceinline__ float b2f(u16 h){
  return __uint_as_float(((u32)h) << 16);
}

// ---------------- fp32 -> bf16 conversion ----------------
__global__ __launch_bounds__(256) void convert_kernel(
    const float* __restrict__ q, const float* __restrict__ k, const float* __restrict__ v,
    const float* __restrict__ Wq, const float* __restrict__ Wk, const float* __restrict__ Wv,
    const float* __restrict__ Wo, u16* __restrict__ ws){
  int y = blockIdx.y;
  const float* src; u16* dst; int n;
  switch(y){
    case 0: src=q;  dst=ws+OFF_XQ; n=4194304; break;
    case 1: src=k;  dst=ws+OFF_XK; n=4194304; break;
    case 2: src=v;  dst=ws+OFF_XV; n=4194304; break;
    case 3: src=Wq; dst=ws+OFF_WQ; n=1048576; break;
    case 4: src=Wk; dst=ws+OFF_WK; n=1048576; break;
    case 5: src=Wv; dst=ws+OFF_WV; n=1048576; break;
    default:src=Wo; dst=ws+OFF_WO; n=1048576; break;
  }
  int idx = (blockIdx.x*256 + threadIdx.x)*4;
  if (idx >= n) return;
  float4 f = *(const float4*)(src + idx);
  ushort4 o;
  o.x = f2b(f.x); o.y = f2b(f.y); o.z = f2b(f.z); o.w = f2b(f.w);
  *(ushort4*)(dst + idx) = o;
}

// ---------------- 128xBN bf16 MFMA GEMM (m97 structure): C = A @ B^T (+bias) ----
template<int MODE>
__global__ __launch_bounds__(256) void gemm_kernel(
    const u16* __restrict__ A0, const u16* __restrict__ B0,
    const float* __restrict__ b0, const float* __restrict__ b1, const float* __restrict__ b2,
    u16* __restrict__ ws, float* __restrict__ outF){
  constexpr int BN = (MODE==1) ? 64 : 128;
  constexpr int NJ = BN/32;                 // n-subtiles per wave
  __shared__ u16 As[128][32];   // linear: global_load_lds dest must be contiguous
  __shared__ u16 Bs[BN][32];
  int z = (MODE==0) ? blockIdx.z : 0;
  const u16* A  = A0 + (size_t)z*4194304u;
  const u16* Bm = B0 + (size_t)z*1048576u;
  const float* bias = (MODE==0) ? (z==0?b0:(z==1?b1:b2)) : b0;
  int tid  = threadIdx.x;
  int lane = tid & 63, wave = tid >> 6;
  int wm = (wave>>1)*64, wn = (wave&1)*(BN/2);
  int m_base = blockIdx.y*128, n_base = blockIdx.x*BN;
  floatx4 acc[4][NJ] = {};
  int fr = lane & 15, fo = (lane>>4)*8;
  int srow = lane >> 2, sseg = (lane & 3)*8;
  u16* AsW0 = &As[wave*32][0];
  u16* AsW1 = &As[wave*32+16][0];
  const u16* Ag0 = A  + (size_t)(m_base + wave*32      + srow)*1024 + sseg;
  const u16* Ag1 = A  + (size_t)(m_base + wave*32 + 16 + srow)*1024 + sseg;
  u16* BsW0; u16* BsW1; const u16* Bg0; const u16* Bg1;
  if constexpr (BN==128){
    BsW0 = &Bs[wave*32][0];    BsW1 = &Bs[wave*32+16][0];
    Bg0 = Bm + (size_t)(n_base + wave*32      + srow)*1024 + sseg;
    Bg1 = Bm + (size_t)(n_base + wave*32 + 16 + srow)*1024 + sseg;
  } else {
    BsW0 = &Bs[wave*16][0];    BsW1 = nullptr;
    Bg0 = Bm + (size_t)(n_base + wave*16 + srow)*1024 + sseg;
    Bg1 = nullptr;
  }
  for (int kb = 0; kb < 1024; kb += 32){
    __builtin_amdgcn_global_load_lds((const u32*)(Ag0 + kb), (u32*)AsW0, 16, 0, 0);
    __builtin_amdgcn_global_load_lds((const u32*)(Ag1 + kb), (u32*)AsW1, 16, 0, 0);
    __builtin_amdgcn_global_load_lds((const u32*)(Bg0 + kb), (u32*)BsW0, 16, 0, 0);
    if constexpr (BN==128)
      __builtin_amdgcn_global_load_lds((const u32*)(Bg1 + kb), (u32*)BsW1, 16, 0, 0);
    __syncthreads();
    bf16x8 af[4], bfr[NJ];
    #pragma unroll
    for (int i=0;i<4;i++)
      af[i]  = *(const bf16x8*)(&As[wm + i*16 + fr][fo]);
    #pragma unroll
    for (int j=0;j<NJ;j++)
      bfr[j] = *(const bf16x8*)(&Bs[wn + j*16 + fr][fo]);
    #pragma unroll
    for (int i=0;i<4;i++)
      #pragma unroll
      for (int j=0;j<NJ;j++)
        acc[i][j] = __builtin_amdgcn_mfma_f32_16x16x32_bf16(af[i], bfr[j], acc[i][j], 0,0,0);
    __syncthreads();
  }
  int col = lane & 15, rb = (lane>>4)*4;
  #pragma unroll
  for (int i=0;i<4;i++){
    #pragma unroll
    for (int j=0;j<NJ;j++){
      int nn = n_base + wn + j*16 + col;
      float bv = bias[nn];
      #pragma unroll
      for (int r=0;r<4;r++){
        int mm = m_base + wm + i*16 + rb + r;
        float v = acc[i][j][r] + bv;
        if (MODE==0){
          if (z==0) v *= 0.125f;              // qh scale 1/sqrt(64), after bias
          int b = mm>>10, t = mm&1023, h = nn>>6, d = nn&63;
          u32 base = (z==0)?OFF_QH:((z==1)?OFF_KH:OFF_VT);
          u32 idx = ((u32)(b*16+h))<<16;
          idx += (z==2) ? ((u32)(d<<10)+(u32)t) : ((u32)(t<<6)+(u32)d);
          ws[base + idx] = f2b(v);
        } else {
          outF[(size_t)mm*1024 + nn] = v;
        }
      }
    }
  }
}

// ---------------- fused attention, single-pass, register-resident P ------------
// Swapped QK^T: mfma(A=K,B=Q) C-layout (q=lane&15, key=(lane>>4)*4+r) is EXACTLY
// the A-frag layout of v_mfma_f32_16x16x16_bf16 (m=lane&15, k=(lane>>4)*4+j), so
// P registers feed PV directly — no shuffles, no LDS P, no recompute.
// Wave owns 256 keys: p4[16] (64 VGPR) holds full unnormalized P^T slice.
// Alignment write goes through a wave-private stride-35 LDS tile (no barriers).
__global__ __launch_bounds__(256) void attn_kernel(
    const u16* __restrict__ ws, const float* __restrict__ rpe_w,
    float* __restrict__ d_out, u16* __restrict__ ctx){
  __shared__ u16   qs[16][64];
  __shared__ float proj[16][33];    // qh . rpe_w[t,:64]
  __shared__ float ssum[4][16][4];  // per-wave {tot,lo,hi} per q
  __shared__ float slds[16][33];    // UNnormalized bucket sums
  __shared__ float linv16[16];
  __shared__ float upool[4224];     // union: Pt[w]=upool+560w (16x35), oacc[w]=upool+1056w (16x66)

  int bid = blockIdx.x;
  int qt = bid & 63, bh = bid >> 6;   // bh = b*16+h
  int q0 = qt * 16;
  int tid = threadIdx.x, lane = tid & 63, wave = tid >> 6;
  int col = lane & 15, g = lane >> 4, rb = g*4, fo = g*8;

  const u16* qh = ws + OFF_QH + (size_t)bh*65536;
  const u16* kh = ws + OFF_KH + (size_t)bh*65536;
  const u16* vT = ws + OFF_VT + (size_t)bh*65536;

  if (tid < 128){
    int r = tid >> 3, c = (tid & 7)*8;
    *(uint4*)(&qs[r][c]) = *(const uint4*)(qh + (size_t)(q0+r)*64 + c);
  }
  for (int i = tid; i < 16*33; i += 256) ((float*)slds)[i] = 0.f;
  __syncthreads();

  for (int i = tid; i < 16*33; i += 256){
    int r = i / 33, t = i - r*33;
    float s = 0.f;
    #pragma unroll
    for (int d=0; d<64; d++) s += b2f(qs[r][d]) * rpe_w[t*128 + d];
    proj[r][t] = s;
  }
  __syncthreads();

  // Q as B-frag: B[n=q=col][k=d=fo+j]
  bf16x8 bq0 = *(const bf16x8*)(&qs[col][fo]);
  bf16x8 bq1 = *(const bf16x8*)(&qs[col][32 + fo]);
  int qg = q0 + col;
  int kw = wave*256;
  float pj_hi = proj[col][0];       // dd <= -16 (key >= q+16)
  float pj_lo = proj[col][32];      // dd >=  16 (key <= q-16)

  // ---- single pass: QK^T + exp -> p4 registers + per-lane sums ----
  floatx4 p4[16];
  float tot = 0.f, lo = 0.f, hi = 0.f;
  const u16* khw = kh + (size_t)(kw + col)*64 + fo;
  #pragma unroll
  for (int it = 0; it < 16; ++it){
    const u16* kp = khw + it*1024;          // +16 keys * 64
    bf16x8 ak0 = *(const bf16x8*)(kp);
    bf16x8 ak1 = *(const bf16x8*)(kp + 32);
    floatx4 s4 = {0.f,0.f,0.f,0.f};
    s4 = __builtin_amdgcn_mfma_f32_16x16x32_bf16(ak0, bq0, s4, 0,0,0);
    s4 = __builtin_amdgcn_mfma_f32_16x16x32_bf16(ak1, bq1, s4, 0,0,0);
    #pragma unroll
    for (int r=0;r<4;r++){
      int key = kw + it*16 + rb + r;
      int dd = qg - key;
      float pjv;
      bool mid = false;
      if      (dd >= 16)  pjv = pj_lo;
      else if (dd <= -16) pjv = pj_hi;
      else { pjv = proj[col][dd+16]; mid = true; }
      float p = __expf(s4[r] + pjv);        // logits ~N(0,1): no max-sub needed
      p4[it][r] = p;
      tot += p;
      if (mid) slds[col][dd+16] = p;        // exact diagonal buckets (unnormalized)
      else if (dd >= 16) lo += p;
      else hi += p;
    }
  }
  tot += __shfl_xor(tot,16); tot += __shfl_xor(tot,32);
  lo  += __shfl_xor(lo, 16); lo  += __shfl_xor(lo, 32);
  hi  += __shfl_xor(hi, 16); hi  += __shfl_xor(hi, 32);
  if (lane < 16){
    ssum[wave][lane][0] = tot; ssum[wave][lane][1] = lo; ssum[wave][lane][2] = hi;
  }
  __syncthreads();
  if (tid < 16){
    float T = ssum[0][tid][0]+ssum[1][tid][0]+ssum[2][tid][0]+ssum[3][tid][0];
    float L = ssum[0][tid][1]+ssum[1][tid][1]+ssum[2][tid][1]+ssum[3][tid][1];
    float H = ssum[0][tid][2]+ssum[1][tid][2]+ssum[2][tid][2]+ssum[3][tid][2];
    linv16[tid] = 1.f / T;
    slds[tid][32] = L;    // bucket t=32 (key <= q-16), unnormalized
    slds[tid][0]  = H;    // bucket t=0  (key >= q+16), unnormalized
  }
  __syncthreads();
  float li_c = linv16[col];

  // ---- PV from registers (16x16x16 MFMA) + alignment via LDS round-trip ----
  floatx4 o4[4] = {};
  float* Ptw = upool + wave*560;            // [16][35] f32, wave-private
  float* outA = d_out + 4194304u + ((size_t)(bh*1024 + q0))*1024;
  int rq = lane >> 2, cb = (lane & 3)*8;    // read-back mapping
  #pragma unroll
  for (int it = 0; it < 16; ++it){
    int kbase = kw + it*16;
    bf16x4 af;
    af[0] = (short)f2b(p4[it][0]);
    af[1] = (short)f2b(p4[it][1]);
    af[2] = (short)f2b(p4[it][2]);
    af[3] = (short)f2b(p4[it][3]);
    #pragma unroll
    for (int dt=0; dt<4; ++dt){
      bf16x4 bv = *(const bf16x4*)(vT + (size_t)(dt*16 + col)*1024 + kbase + rb);
      // VALU->MFMA src hazard: s_nop 1. o4 is SrcC/D (0 wait, hw-chained).
      asm("s_nop 1\n\tv_mfma_f32_16x16x16_bf16 %0, %1, %2, %0"
          : "+v"(o4[dt]) : "v"(af), "v"(bv));
    }
    // normalized alignment -> wave-private LDS (stride 35: ~2-way banks both sides)
    #pragma unroll
    for (int r=0;r<4;r++)
      Ptw[col*35 + (it&1)*16 + rb + r] = p4[it][r] * li_c;
    if (it & 1){
      const float* prow = Ptw + rq*35 + cb;
      float4 w0 = {prow[0],prow[1],prow[2],prow[3]};
      float4 w1 = {prow[4],prow[5],prow[6],prow[7]};
      float* gp = outA + (size_t)rq*1024 + kw + (it-1)*16 + cb;
      *(float4*)gp = w0; *(float4*)(gp+4) = w1;
    }
  }
  // MFMA(o4) -> VALU read hazard guard
  asm volatile("s_nop 7\n\ts_nop 7");
  __syncthreads();                          // all Pt reads done; upool reused as oacc
  {
    float* oa = upool + wave*1056;          // [16][66] f32
    #pragma unroll
    for (int dt=0; dt<4; ++dt)
      #pragma unroll
      for (int r=0;r<4;++r)
        oa[(rb+r)*66 + dt*16 + col] = o4[dt][r];
  }
  __syncthreads();

  // epilogue: O = sum_waves + RPE-V bucket contribution, all x 1/l
  {
    int b = bh >> 4, h = bh & 15, d2 = wave*16 + col;
    #pragma unroll
    for (int r=0;r<4;++r){
      int row = rb + r;
      float ov = upool[row*66 + d2] + upool[1056 + row*66 + d2]
               + upool[2112 + row*66 + d2] + upool[3168 + row*66 + d2];
      float sv = 0.f;
      #pragma unroll
      for (int t=0;t<33;++t) sv += slds[row][t] * rpe_w[t*128 + 64 + d2];
      float li_r = linv16[row];
      ctx[((size_t)(b*1024 + q0 + row))*1024 + h*64 + d2] = f2b((ov + sv) * li_r);
    }
  }
}

extern "C" void kernel_launch(void* const* d_in, const int* in_sizes, int n_in,
                              void* d_out, int out_size, void* d_ws, size_t ws_size,
                              hipStream_t stream){
  const float* q  = (const float*)d_in[0];
  const float* k  = (const float*)d_in[1];
  const float* v  = (const float*)d_in[2];
  const float* Wq = (const float*)d_in[3];
  const float* bq = (const float*)d_in[4];
  const float* Wk = (const float*)d_in[5];
  const float* bk = (const float*)d_in[6];
  const float* Wv = (const float*)d_in[7];
  const float* bv = (const float*)d_in[8];
  const float* rpe= (const float*)d_in[9];
  const float* Wo = (const float*)d_in[10];
  const float* bo = (const float*)d_in[11];
  u16* ws = (u16*)d_ws;
  float* out = (float*)d_out;

  convert_kernel<<<dim3(4096,7), 256, 0, stream>>>(q,k,v,Wq,Wk,Wv,Wo, ws);
  gemm_kernel<0><<<dim3(8,32,3), 256, 0, stream>>>(ws+OFF_XQ, ws+OFF_WQ, bq, bk, bv, ws, nullptr);
  attn_kernel<<<dim3(4096), 256, 0, stream>>>(ws, rpe, out, ws+OFF_CTX);
  gemm_kernel<1><<<dim3(16,32), 256, 0, stream>>>(ws+OFF_CTX, ws+OFF_WO, bo, nullptr, nullptr, ws, out);
}

// Round 5
// 579.110 us; speedup vs baseline: 1.2083x; 1.2083x over previous
//
#include <hip/hip_runtime.h>
#include <stdint.h>

typedef unsigned short u16;
typedef unsigned int   u32;
typedef short bf16x8 __attribute__((ext_vector_type(8)));
typedef float floatx4 __attribute__((ext_vector_type(4)));

// ---- ws layout (u16 element offsets), total 64 MB ----
#define OFF_XQ   0u
#define OFF_XK   4194304u
#define OFF_XV   8388608u
#define OFF_WQ   12582912u
#define OFF_WK   13631488u
#define OFF_WV   14680064u
#define OFF_WO   15728640u
#define OFF_QH   16777216u
#define OFF_KH   20971520u
#define OFF_VT   25165824u
#define OFF_CTX  29360128u

__device__ __forceinline__ u16 f2b(float f){
  u32 u = __float_as_uint(f);
  u = (u + 0x7fffu + ((u >> 16) & 1u)) >> 16;
  return (u16)u;
}
__device__ __forceinline__ float b2f(u16 h){
  return __uint_as_float(((u32)h) << 16);
}

// ---------------- fp32 -> bf16 conversion ----------------
__global__ __launch_bounds__(256) void convert_kernel(
    const float* __restrict__ q, const float* __restrict__ k, const float* __restrict__ v,
    const float* __restrict__ Wq, const float* __restrict__ Wk, const float* __restrict__ Wv,
    const float* __restrict__ Wo, u16* __restrict__ ws){
  int y = blockIdx.y;
  const float* src; u16* dst; int n;
  switch(y){
    case 0: src=q;  dst=ws+OFF_XQ; n=4194304; break;
    case 1: src=k;  dst=ws+OFF_XK; n=4194304; break;
    case 2: src=v;  dst=ws+OFF_XV; n=4194304; break;
    case 3: src=Wq; dst=ws+OFF_WQ; n=1048576; break;
    case 4: src=Wk; dst=ws+OFF_WK; n=1048576; break;
    case 5: src=Wv; dst=ws+OFF_WV; n=1048576; break;
    default:src=Wo; dst=ws+OFF_WO; n=1048576; break;
  }
  int idx = (blockIdx.x*256 + threadIdx.x)*4;
  if (idx >= n) return;
  float4 f = *(const float4*)(src + idx);
  ushort4 o;
  o.x = f2b(f.x); o.y = f2b(f.y); o.z = f2b(f.z); o.w = f2b(f.w);
  *(ushort4*)(dst + idx) = o;
}

// ---------------- 128xBN bf16 MFMA GEMM (m97 structure): C = A @ B^T (+bias) ----
// MODE 0: BN=128, z in {0,1}: Q (scaled) and K projections -> [b,h,t,d] bf16.
// MODE 1: BN=64, output projection, fp32 store to d_out.  (512 blocks = 2/CU)
// MODE 2: BN=64, V projection TRANSPOSED: C' = Wv @ Xv^T (A=Wv[1024][1024],
//         B=Xv[4096][1024]). C'[i=(h,d)][m=(b,t)] rows are contiguous in t ->
//         vT store is fully coalesced (kills the stride-2KB scatter). Bias on mm.
template<int MODE>
__global__ __launch_bounds__(256) void gemm_kernel(
    const u16* __restrict__ A0, const u16* __restrict__ B0,
    const float* __restrict__ b0, const float* __restrict__ b1, const float* __restrict__ b2,
    u16* __restrict__ ws, float* __restrict__ outF){
  constexpr int BN = (MODE==0) ? 128 : 64;
  constexpr int NJ = BN/32;                 // n-subtiles per wave
  __shared__ u16 As[128][32];   // linear: global_load_lds dest must be contiguous
  __shared__ u16 Bs[BN][32];
  int z = (MODE==0) ? blockIdx.z : 0;
  const u16* A  = A0 + (size_t)z*4194304u;
  const u16* Bm = B0 + (size_t)z*1048576u;
  const float* bias = (MODE==0) ? (z==0?b0:b1) : b0;
  int tid  = threadIdx.x;
  int lane = tid & 63, wave = tid >> 6;
  int wm = (wave>>1)*64, wn = (wave&1)*(BN/2);
  int m_base = blockIdx.y*128, n_base = blockIdx.x*BN;
  floatx4 acc[4][NJ] = {};
  int fr = lane & 15, fo = (lane>>4)*8;
  int srow = lane >> 2, sseg = (lane & 3)*8;
  u16* AsW0 = &As[wave*32][0];
  u16* AsW1 = &As[wave*32+16][0];
  const u16* Ag0 = A  + (size_t)(m_base + wave*32      + srow)*1024 + sseg;
  const u16* Ag1 = A  + (size_t)(m_base + wave*32 + 16 + srow)*1024 + sseg;
  u16* BsW0; u16* BsW1; const u16* Bg0; const u16* Bg1;
  if constexpr (BN==128){
    BsW0 = &Bs[wave*32][0];    BsW1 = &Bs[wave*32+16][0];
    Bg0 = Bm + (size_t)(n_base + wave*32      + srow)*1024 + sseg;
    Bg1 = Bm + (size_t)(n_base + wave*32 + 16 + srow)*1024 + sseg;
  } else {
    BsW0 = &Bs[wave*16][0];    BsW1 = nullptr;
    Bg0 = Bm + (size_t)(n_base + wave*16 + srow)*1024 + sseg;
    Bg1 = nullptr;
  }
  for (int kb = 0; kb < 1024; kb += 32){
    __builtin_amdgcn_global_load_lds((const u32*)(Ag0 + kb), (u32*)AsW0, 16, 0, 0);
    __builtin_amdgcn_global_load_lds((const u32*)(Ag1 + kb), (u32*)AsW1, 16, 0, 0);
    __builtin_amdgcn_global_load_lds((const u32*)(Bg0 + kb), (u32*)BsW0, 16, 0, 0);
    if constexpr (BN==128)
      __builtin_amdgcn_global_load_lds((const u32*)(Bg1 + kb), (u32*)BsW1, 16, 0, 0);
    __syncthreads();
    bf16x8 af[4], bfr[NJ];
    #pragma unroll
    for (int i=0;i<4;i++)
      af[i]  = *(const bf16x8*)(&As[wm + i*16 + fr][fo]);
    #pragma unroll
    for (int j=0;j<NJ;j++)
      bfr[j] = *(const bf16x8*)(&Bs[wn + j*16 + fr][fo]);
    #pragma unroll
    for (int i=0;i<4;i++)
      #pragma unroll
      for (int j=0;j<NJ;j++)
        acc[i][j] = __builtin_amdgcn_mfma_f32_16x16x32_bf16(af[i], bfr[j], acc[i][j], 0,0,0);
    __syncthreads();
  }
  int col = lane & 15, rb = (lane>>4)*4;
  #pragma unroll
  for (int i=0;i<4;i++){
    #pragma unroll
    for (int j=0;j<NJ;j++){
      int nn = n_base + wn + j*16 + col;
      float bvn = (MODE==2) ? 0.f : bias[nn];
      #pragma unroll
      for (int r=0;r<4;r++){
        int mm = m_base + wm + i*16 + rb + r;
        if constexpr (MODE==0){
          float v = acc[i][j][r] + bvn;
          if (z==0) v *= 0.125f;              // qh scale 1/sqrt(64), after bias
          int b = mm>>10, t = mm&1023, h = nn>>6, d = nn&63;
          u32 base = (z==0)?OFF_QH:OFF_KH;
          u32 idx = (((u32)(b*16+h))<<16) + ((u32)(t<<6)) + (u32)d;
          ws[base + idx] = f2b(v);
        } else if constexpr (MODE==1){
          outF[(size_t)mm*1024 + nn] = acc[i][j][r] + bvn;
        } else {
          // MODE2: mm = i = h*64+d, nn = b*1024+t; coalesced in t
          float v = acc[i][j][r] + bias[mm];
          int h = mm>>6, d = mm&63, b = nn>>10, t = nn&1023;
          u32 idx = (((u32)(b*16+h))<<16) + ((u32)(d<<10)) + (u32)t;
          ws[OFF_VT + idx] = f2b(v);
        }
      }
    }
  }
}

// ---------------- fused attention (R0 structure, rpev staging dropped) ---------
// One block = (b,h, 16-query tile). P resident in LDS; 39.5KB LDS -> 4 blocks/CU.
__global__ __launch_bounds__(256) void attn_kernel(
    const u16* __restrict__ ws, const float* __restrict__ rpe_w,
    float* __restrict__ d_out, u16* __restrict__ ctx){
  __shared__ u16   P[16][1032];     // unnormalized exp(energy), bf16; stride 1032 (2-way = free)
  __shared__ u16   qs[16][64];
  __shared__ float proj[16][33];    // qh . rpe_w[t,:64]
  __shared__ float sacc[16][3];     // tot, low(t=32), high(t=0)
  __shared__ float slds[16][33];    // bucket sums (unnormalized)
  __shared__ float linv[16];

  int bid = blockIdx.x;
  int qt = bid & 63, bh = bid >> 6;   // bh = b*16+h
  int q0 = qt * 16;
  int tid = threadIdx.x, lane = tid & 63, wave = tid >> 6;

  const u16* qh = ws + OFF_QH + (size_t)bh*65536;
  const u16* kh = ws + OFF_KH + (size_t)bh*65536;
  const u16* vT = ws + OFF_VT + (size_t)bh*65536;

  if (tid < 128){
    int r = tid >> 3, c = (tid & 7)*8;
    *(uint4*)(&qs[r][c]) = *(const uint4*)(qh + (size_t)(q0+r)*64 + c);
  }
  if (tid < 48) ((float*)sacc)[tid] = 0.f;
  __syncthreads();

  for (int i = tid; i < 16*33; i += 256){
    int r = i / 33, t = i - r*33;
    float s = 0.f;
    #pragma unroll
    for (int d=0; d<64; d++) s += b2f(qs[r][d]) * rpe_w[t*128 + d];
    proj[r][t] = s;
  }
  __syncthreads();

  int col = lane & 15, rb = (lane>>4)*4, fo = (lane>>4)*8;
  // A-frags (qh) — same for all waves: A[m=lane&15][k=(lane>>4)*8+j]
  bf16x8 aq0 = *(const bf16x8*)(&qs[col][fo]);
  bf16x8 aq1 = *(const bf16x8*)(&qs[col][32 + fo]);

  float tot[4] = {0,0,0,0}, lo[4] = {0,0,0,0}, hi[4] = {0,0,0,0};
  for (int kb = 0; kb < 1024; kb += 64){
    int key = kb + wave*16 + col;                 // B n-index = lane&15
    const u16* kp = kh + (size_t)key*64 + fo;
    bf16x8 bk0 = *(const bf16x8*)(kp);
    bf16x8 bk1 = *(const bf16x8*)(kp + 32);
    floatx4 s4 = {0.f,0.f,0.f,0.f};
    s4 = __builtin_amdgcn_mfma_f32_16x16x32_bf16(aq0, bk0, s4, 0,0,0);
    s4 = __builtin_amdgcn_mfma_f32_16x16x32_bf16(aq1, bk1, s4, 0,0,0);
    #pragma unroll
    for (int r=0;r<4;r++){
      int row = rb + r;
      int qg = q0 + row;
      int dd = qg - key;
      int bkt = min(max(dd, -16), 16) + 16;
      float p = __expf(s4[r] + proj[row][bkt]);   // logits ~N(0,1): exp w/o max-sub is safe
      P[row][key] = f2b(p);
      tot[r] += p;
      if      (key <= qg - 16) lo[r] += p;        // bucket t=32
      else if (key >= qg + 16) hi[r] += p;        // bucket t=0
    }
  }
  #pragma unroll
  for (int r=0;r<4;r++){
    #pragma unroll
    for (int m=8;m>=1;m>>=1){
      tot[r] += __shfl_xor(tot[r], m, 16);
      lo[r]  += __shfl_xor(lo[r],  m, 16);
      hi[r]  += __shfl_xor(hi[r],  m, 16);
    }
  }
  if (col == 0){
    #pragma unroll
    for (int r=0;r<4;r++){
      atomicAdd(&sacc[rb+r][0], tot[r]);
      atomicAdd(&sacc[rb+r][1], lo[r]);
      atomicAdd(&sacc[rb+r][2], hi[r]);
    }
  }
  __syncthreads();

  if (tid < 16){
    linv[tid] = 1.f / sacc[tid][0];
    slds[tid][32] = sacc[tid][1];
    slds[tid][0]  = sacc[tid][2];
  }
  for (int i = tid; i < 16*31; i += 256){
    int r = i / 31, t = 1 + (i - r*31);
    int kk = q0 + r + 16 - t;                     // exact diagonal for middle buckets
    slds[r][t] = (kk >= 0 && kk < 1024) ? b2f(P[r][kk]) : 0.f;
  }
  __syncthreads();

  // alignment write: fp32, coalesced float4
  {
    int row = tid >> 4, c0 = (tid & 15)*4;
    float li = linv[row];
    float* outA = d_out + 4194304u + ((size_t)(bh*1024 + q0 + row))*1024;
    #pragma unroll
    for (int i=0;i<16;i++){
      int kcol = c0 + i*64;
      ushort4 pv = *(const ushort4*)(&P[row][kcol]);
      float4 o;
      o.x = b2f(pv.x)*li; o.y = b2f(pv.y)*li;
      o.z = b2f(pv.z)*li; o.w = b2f(pv.w)*li;
      *(float4*)(outA + kcol) = o;
    }
  }

  // PV: wave handles 16 head-dims; A from LDS P, B from vT (contiguous per lane)
  floatx4 o4 = {0.f,0.f,0.f,0.f};
  int n0 = wave*16;
  {
    const u16* vbase = vT + (size_t)(n0 + col)*1024;
    for (int kk = 0; kk < 1024; kk += 32){
      bf16x8 ap  = *(const bf16x8*)(&P[col][kk + fo]);
      bf16x8 bv8 = *(const bf16x8*)(vbase + kk + fo);
      o4 = __builtin_amdgcn_mfma_f32_16x16x32_bf16(ap, bv8, o4, 0,0,0);
    }
  }
  {
    int b = bh >> 4, h = bh & 15;
    int d = n0 + col;
    float sv[4] = {0.f,0.f,0.f,0.f};
    const float* rv = rpe_w + 64 + d;             // L2-hot 16KB table, read direct
    #pragma unroll
    for (int t=0;t<33;t++){
      float rvt = rv[t*128];
      #pragma unroll
      for (int r=0;r<4;r++) sv[r] += slds[rb+r][t]*rvt;
    }
    #pragma unroll
    for (int r=0;r<4;r++){
      int row = rb + r;
      float v = (o4[r] + sv[r]) * linv[row];
      ctx[((size_t)(b*1024 + q0 + row))*1024 + h*64 + d] = f2b(v);
    }
  }
}

extern "C" void kernel_launch(void* const* d_in, const int* in_sizes, int n_in,
                              void* d_out, int out_size, void* d_ws, size_t ws_size,
                              hipStream_t stream){
  const float* q  = (const float*)d_in[0];
  const float* k  = (const float*)d_in[1];
  const float* v  = (const float*)d_in[2];
  const float* Wq = (const float*)d_in[3];
  const float* bq = (const float*)d_in[4];
  const float* Wk = (const float*)d_in[5];
  const float* bk = (const float*)d_in[6];
  const float* Wv = (const float*)d_in[7];
  const float* bv = (const float*)d_in[8];
  const float* rpe= (const float*)d_in[9];
  const float* Wo = (const float*)d_in[10];
  const float* bo = (const float*)d_in[11];
  u16* ws = (u16*)d_ws;
  float* out = (float*)d_out;

  convert_kernel<<<dim3(4096,7), 256, 0, stream>>>(q,k,v,Wq,Wk,Wv,Wo, ws);
  gemm_kernel<0><<<dim3(8,32,2), 256, 0, stream>>>(ws+OFF_XQ, ws+OFF_WQ, bq, bk, nullptr, ws, nullptr);
  gemm_kernel<2><<<dim3(64,8),   256, 0, stream>>>(ws+OFF_WV, ws+OFF_XV, bv, nullptr, nullptr, ws, nullptr);
  attn_kernel<<<dim3(4096), 256, 0, stream>>>(ws, rpe, out, ws+OFF_CTX);
  gemm_kernel<1><<<dim3(16,32), 256, 0, stream>>>(ws+OFF_CTX, ws+OFF_WO, bo, nullptr, nullptr, ws, out);
}

// Round 6
// 522.636 us; speedup vs baseline: 1.3389x; 1.1081x over previous
//
#include <hip/hip_runtime.h>
#include <stdint.h>

typedef unsigned short u16;
typedef unsigned int   u32;
typedef short bf16x8 __attribute__((ext_vector_type(8)));
typedef float floatx4 __attribute__((ext_vector_type(4)));

// ---- ws layout (u16 element offsets), total 64 MB ----
#define OFF_XQ   0u
#define OFF_XK   4194304u
#define OFF_XV   8388608u
#define OFF_WQ   12582912u
#define OFF_WK   13631488u
#define OFF_WV   14680064u
#define OFF_WO   15728640u
#define OFF_QH   16777216u
#define OFF_KH   20971520u
#define OFF_VT   25165824u
#define OFF_CTX  29360128u

__device__ __forceinline__ u16 f2b(float f){
  u32 u = __float_as_uint(f);
  u = (u + 0x7fffu + ((u >> 16) & 1u)) >> 16;
  return (u16)u;
}
__device__ __forceinline__ float b2f(u16 h){
  return __uint_as_float(((u32)h) << 16);
}

// ---------------- fp32 -> bf16 conversion (exact 1-D grid, 16384 blocks) -------
__global__ __launch_bounds__(256) void convert_kernel(
    const float* __restrict__ q, const float* __restrict__ k, const float* __restrict__ v,
    const float* __restrict__ Wq, const float* __restrict__ Wk, const float* __restrict__ Wv,
    const float* __restrict__ Wo, u16* __restrict__ ws){
  int bid = blockIdx.x;
  int y, local;
  if (bid < 12288){ y = bid >> 12; local = bid & 4095; }
  else { int t = bid - 12288; y = 3 + (t >> 10); local = t & 1023; }
  const float* src; u16* dst;
  switch(y){
    case 0: src=q;  dst=ws+OFF_XQ; break;
    case 1: src=k;  dst=ws+OFF_XK; break;
    case 2: src=v;  dst=ws+OFF_XV; break;
    case 3: src=Wq; dst=ws+OFF_WQ; break;
    case 4: src=Wk; dst=ws+OFF_WK; break;
    case 5: src=Wv; dst=ws+OFF_WV; break;
    default:src=Wo; dst=ws+OFF_WO; break;
  }
  int idx = (local*256 + threadIdx.x)*4;
  float4 f = *(const float4*)(src + idx);
  ushort4 o;
  o.x = f2b(f.x); o.y = f2b(f.y); o.z = f2b(f.z); o.w = f2b(f.w);
  *(ushort4*)(dst + idx) = o;
}

// ---------------- 128x64 bf16 MFMA GEMM (m97 staging): C = A @ B^T (+bias) -----
// MODE 0: fused QKV projections, ONE launch dim3(16,32,3) = 1536 blocks = 6/CU:
//   z=0: Q = Xq@Wq^T (scaled), z=1: K = Xk@Wk^T  -> [b,h,t,d] bf16
//   z=2: V TRANSPOSED: C' = Wv@Xv^T -> vT[b,h,d,t] coalesced (flat remap of x,y)
// MODE 1: output projection, fp32 store to d_out. grid (16,32) = 512 blocks.
template<int MODE>
__global__ __launch_bounds__(256) void gemm_kernel(
    const u16* __restrict__ A0, const u16* __restrict__ B0,
    const float* __restrict__ b0, const float* __restrict__ b1, const float* __restrict__ b2,
    u16* __restrict__ ws, float* __restrict__ outF){
  __shared__ u16 As[128][32];   // linear: global_load_lds dest must be contiguous
  __shared__ u16 Bs[64][32];
  int z = (MODE==0) ? blockIdx.z : 0;
  const u16* A; const u16* Bm;
  int m_base, n_base;
  if constexpr (MODE==0){
    if (z < 2){
      A  = ws + (z==0 ? OFF_XQ : OFF_XK);
      Bm = ws + (z==0 ? OFF_WQ : OFF_WK);
      m_base = blockIdx.y*128; n_base = blockIdx.x*64;
    } else {
      A  = ws + OFF_WV;  Bm = ws + OFF_XV;     // C' = Wv @ Xv^T
      int flat = blockIdx.y*16 + blockIdx.x;   // 0..511
      m_base = (flat>>6)*128; n_base = (flat&63)*64;
    }
  } else {
    A = A0; Bm = B0;
    m_base = blockIdx.y*128; n_base = blockIdx.x*64;
  }
  int tid  = threadIdx.x;
  int lane = tid & 63, wave = tid >> 6;
  int wm = (wave>>1)*64, wn = (wave&1)*32;
  floatx4 acc[4][2] = {};
  int fr = lane & 15, fo = (lane>>4)*8;
  int srow = lane >> 2, sseg = (lane & 3)*8;
  u16* AsW0 = &As[wave*32][0];
  u16* AsW1 = &As[wave*32+16][0];
  u16* BsW0 = &Bs[wave*16][0];
  const u16* Ag0 = A  + (size_t)(m_base + wave*32      + srow)*1024 + sseg;
  const u16* Ag1 = A  + (size_t)(m_base + wave*32 + 16 + srow)*1024 + sseg;
  const u16* Bg0 = Bm + (size_t)(n_base + wave*16      + srow)*1024 + sseg;
  for (int kb = 0; kb < 1024; kb += 32){
    __builtin_amdgcn_global_load_lds((const u32*)(Ag0 + kb), (u32*)AsW0, 16, 0, 0);
    __builtin_amdgcn_global_load_lds((const u32*)(Ag1 + kb), (u32*)AsW1, 16, 0, 0);
    __builtin_amdgcn_global_load_lds((const u32*)(Bg0 + kb), (u32*)BsW0, 16, 0, 0);
    __syncthreads();
    bf16x8 af[4], bfr[2];
    #pragma unroll
    for (int i=0;i<4;i++)
      af[i]  = *(const bf16x8*)(&As[wm + i*16 + fr][fo]);
    #pragma unroll
    for (int j=0;j<2;j++)
      bfr[j] = *(const bf16x8*)(&Bs[wn + j*16 + fr][fo]);
    #pragma unroll
    for (int i=0;i<4;i++)
      #pragma unroll
      for (int j=0;j<2;j++)
        acc[i][j] = __builtin_amdgcn_mfma_f32_16x16x32_bf16(af[i], bfr[j], acc[i][j], 0,0,0);
    __syncthreads();
  }
  int col = lane & 15, rb = (lane>>4)*4;
  #pragma unroll
  for (int i=0;i<4;i++){
    #pragma unroll
    for (int j=0;j<2;j++){
      int nn = n_base + wn + j*16 + col;
      #pragma unroll
      for (int r=0;r<4;r++){
        int mm = m_base + wm + i*16 + rb + r;
        float v = acc[i][j][r];
        if constexpr (MODE==1){
          outF[(size_t)mm*1024 + nn] = v + b0[nn];
        } else {
          if (z < 2){
            v += (z==0 ? b0 : b1)[nn];
            if (z==0) v *= 0.125f;            // qh scale 1/sqrt(64), after bias
            int b = mm>>10, t = mm&1023, h = nn>>6, d = nn&63;
            u32 base = (z==0)?OFF_QH:OFF_KH;
            ws[base + (((u32)(b*16+h))<<16) + ((u32)(t<<6)) + (u32)d] = f2b(v);
          } else {
            v += b2[mm];                       // bias indexed by output channel
            int h = mm>>6, d = mm&63, b = nn>>10, t = nn&1023;
            ws[OFF_VT + (((u32)(b*16+h))<<16) + ((u32)(d<<10)) + (u32)t] = f2b(v);
          }
        }
      }
    }
  }
}

// ---------------- fused attention (R5 structure + latency micro-fixes) ---------
// One block = (b,h, 16-query tile). 40KB LDS -> 4 blocks/CU.
// Changes vs R5: proj computed via 2 MFMAs/wave (was ~132 scalar L2 loads/thread
// serial phase); LDS atomics -> per-wave ssum staging; unroll 4 on QK/PV loops.
__global__ __launch_bounds__(256) void attn_kernel(
    const u16* __restrict__ ws, const float* __restrict__ rpe_w,
    float* __restrict__ d_out, u16* __restrict__ ctx){
  __shared__ u16   P[16][1032];     // unnormalized exp(energy), bf16; stride 1032 (2-way = free)
  __shared__ u16   qs[16][64];
  __shared__ float proj[16][33];    // qh . rpe_w[t,:64]
  __shared__ float ssum[4][16][3];  // per-wave {tot,lo,hi} per q-row
  __shared__ float slds[16][33];    // bucket sums (unnormalized)
  __shared__ float linv[16];

  int bid = blockIdx.x;
  int qt = bid & 63, bh = bid >> 6;   // bh = b*16+h
  int q0 = qt * 16;
  int tid = threadIdx.x, lane = tid & 63, wave = tid >> 6;
  int col = lane & 15, rb = (lane>>4)*4, fo = (lane>>4)*8;

  const u16* qh = ws + OFF_QH + (size_t)bh*65536;
  const u16* kh = ws + OFF_KH + (size_t)bh*65536;
  const u16* vT = ws + OFF_VT + (size_t)bh*65536;

  if (tid < 128){
    int r = tid >> 3, c = (tid & 7)*8;
    *(uint4*)(&qs[r][c]) = *(const uint4*)(qh + (size_t)(q0+r)*64 + c);
  }
  __syncthreads();

  // A-frags (qh): A[m=lane&15][k=(lane>>4)*8+j]  (identical per-lane pattern as B-frag)
  bf16x8 aq0 = *(const bf16x8*)(&qs[col][fo]);
  bf16x8 aq1 = *(const bf16x8*)(&qs[col][32 + fo]);

  // proj[q][t] = qh[q]-dot-rpe_w[t,:64] via mfma(A=rpe_t, B=qh): C[m=t][n=q].
  // waves 0..2 cover t = wave*16 + (rb+r); wave 2 keeps only t==32.
  if (wave < 3){
    int t_r = wave*16 + col;
    int t_c = min(t_r, 32);                   // clamp OOB fragment rows
    const float* rp = rpe_w + t_c*128 + fo;
    bf16x8 ar0, ar1;
    #pragma unroll
    for (int j=0;j<8;j++){ ar0[j] = (short)f2b(rp[j]); ar1[j] = (short)f2b(rp[32+j]); }
    floatx4 s4 = {0.f,0.f,0.f,0.f};
    s4 = __builtin_amdgcn_mfma_f32_16x16x32_bf16(ar0, aq0, s4, 0,0,0);
    s4 = __builtin_amdgcn_mfma_f32_16x16x32_bf16(ar1, aq1, s4, 0,0,0);
    #pragma unroll
    for (int r=0;r<4;r++){
      int t_out = wave*16 + rb + r;
      if (t_out <= 32) proj[col][t_out] = s4[r];
    }
  }
  __syncthreads();

  float tot[4] = {0,0,0,0}, lo[4] = {0,0,0,0}, hi[4] = {0,0,0,0};
  #pragma unroll 4
  for (int kb = 0; kb < 1024; kb += 64){
    int key = kb + wave*16 + col;                 // B n-index = lane&15
    const u16* kp = kh + (size_t)key*64 + fo;
    bf16x8 bk0 = *(const bf16x8*)(kp);
    bf16x8 bk1 = *(const bf16x8*)(kp + 32);
    floatx4 s4 = {0.f,0.f,0.f,0.f};
    s4 = __builtin_amdgcn_mfma_f32_16x16x32_bf16(aq0, bk0, s4, 0,0,0);
    s4 = __builtin_amdgcn_mfma_f32_16x16x32_bf16(aq1, bk1, s4, 0,0,0);
    #pragma unroll
    for (int r=0;r<4;r++){
      int row = rb + r;
      int qg = q0 + row;
      int dd = qg - key;
      int bkt = min(max(dd, -16), 16) + 16;
      float p = __expf(s4[r] + proj[row][bkt]);   // logits ~N(0,1): exp w/o max-sub is safe
      P[row][key] = f2b(p);
      tot[r] += p;
      if      (key <= qg - 16) lo[r] += p;        // bucket t=32
      else if (key >= qg + 16) hi[r] += p;        // bucket t=0
    }
  }
  #pragma unroll
  for (int r=0;r<4;r++){
    #pragma unroll
    for (int m=8;m>=1;m>>=1){
      tot[r] += __shfl_xor(tot[r], m, 16);
      lo[r]  += __shfl_xor(lo[r],  m, 16);
      hi[r]  += __shfl_xor(hi[r],  m, 16);
    }
  }
  if (col == 0){                                  // lanes {0,16,32,48}: rows rb..rb+3
    #pragma unroll
    for (int r=0;r<4;r++){
      ssum[wave][rb+r][0] = tot[r];
      ssum[wave][rb+r][1] = lo[r];
      ssum[wave][rb+r][2] = hi[r];
    }
  }
  __syncthreads();

  if (tid < 16){
    float T = ssum[0][tid][0]+ssum[1][tid][0]+ssum[2][tid][0]+ssum[3][tid][0];
    float L = ssum[0][tid][1]+ssum[1][tid][1]+ssum[2][tid][1]+ssum[3][tid][1];
    float H = ssum[0][tid][2]+ssum[1][tid][2]+ssum[2][tid][2]+ssum[3][tid][2];
    linv[tid] = 1.f / T;
    slds[tid][32] = L;
    slds[tid][0]  = H;
  }
  for (int i = tid; i < 16*31; i += 256){
    int r = i / 31, t = 1 + (i - r*31);
    int kk = q0 + r + 16 - t;                     // exact diagonal for middle buckets
    slds[r][t] = (kk >= 0 && kk < 1024) ? b2f(P[r][kk]) : 0.f;
  }
  __syncthreads();

  // alignment write: fp32, coalesced float4
  {
    int row = tid >> 4, c0 = (tid & 15)*4;
    float li = linv[row];
    float* outA = d_out + 4194304u + ((size_t)(bh*1024 + q0 + row))*1024;
    #pragma unroll
    for (int i=0;i<16;i++){
      int kcol = c0 + i*64;
      ushort4 pv = *(const ushort4*)(&P[row][kcol]);
      float4 o;
      o.x = b2f(pv.x)*li; o.y = b2f(pv.y)*li;
      o.z = b2f(pv.z)*li; o.w = b2f(pv.w)*li;
      *(float4*)(outA + kcol) = o;
    }
  }

  // PV: wave handles 16 head-dims; A from LDS P, B from vT (contiguous per lane)
  floatx4 o4 = {0.f,0.f,0.f,0.f};
  int n0 = wave*16;
  {
    const u16* vbase = vT + (size_t)(n0 + col)*1024;
    #pragma unroll 4
    for (int kk = 0; kk < 1024; kk += 32){
      bf16x8 ap  = *(const bf16x8*)(&P[col][kk + fo]);
      bf16x8 bv8 = *(const bf16x8*)(vbase + kk + fo);
      o4 = __builtin_amdgcn_mfma_f32_16x16x32_bf16(ap, bv8, o4, 0,0,0);
    }
  }
  {
    int b = bh >> 4, h = bh & 15;
    int d = n0 + col;
    float sv[4] = {0.f,0.f,0.f,0.f};
    const float* rv = rpe_w + 64 + d;             // L2-hot 16KB table, read direct
    #pragma unroll
    for (int t=0;t<33;t++){
      float rvt = rv[t*128];
      #pragma unroll
      for (int r=0;r<4;r++) sv[r] += slds[rb+r][t]*rvt;
    }
    #pragma unroll
    for (int r=0;r<4;r++){
      int row = rb + r;
      float v = (o4[r] + sv[r]) * linv[row];
      ctx[((size_t)(b*1024 + q0 + row))*1024 + h*64 + d] = f2b(v);
    }
  }
}

extern "C" void kernel_launch(void* const* d_in, const int* in_sizes, int n_in,
                              void* d_out, int out_size, void* d_ws, size_t ws_size,
                              hipStream_t stream){
  const float* q  = (const float*)d_in[0];
  const float* k  = (const float*)d_in[1];
  const float* v  = (const float*)d_in[2];
  const float* Wq = (const float*)d_in[3];
  const float* bq = (const float*)d_in[4];
  const float* Wk = (const float*)d_in[5];
  const float* bk = (const float*)d_in[6];
  const float* Wv = (const float*)d_in[7];
  const float* bv = (const float*)d_in[8];
  const float* rpe= (const float*)d_in[9];
  const float* Wo = (const float*)d_in[10];
  const float* bo = (const float*)d_in[11];
  u16* ws = (u16*)d_ws;
  float* out = (float*)d_out;

  convert_kernel<<<dim3(16384), 256, 0, stream>>>(q,k,v,Wq,Wk,Wv,Wo, ws);
  gemm_kernel<0><<<dim3(16,32,3), 256, 0, stream>>>(nullptr, nullptr, bq, bk, bv, ws, nullptr);
  attn_kernel<<<dim3(4096), 256, 0, stream>>>(ws, rpe, out, ws+OFF_CTX);
  gemm_kernel<1><<<dim3(16,32), 256, 0, stream>>>(ws+OFF_CTX, ws+OFF_WO, bo, nullptr, nullptr, ws, out);
}